// Round 2
// baseline (270.688 us; speedup 1.0000x reference)
//
#include <hip/hip_runtime.h>

// out[b, t, n, :] = x[b, (t - shift[n]) % 16, n, :]
// x: (B=16, T=16, N=196, c=768) fp32, contiguous.
//
// shift[n] closed form (m=1): w=n%7, h=n/7, a=w%3, b=h%3:
//   (0,0)->-4 (0,1)->1 (0,2)->2
//   (1,0)->-1 (1,1)-> (n==8 ? 0 : -1)   // sticky inv_state: only i=8 sees inv==0
//   (1,2)->3  (2,0)->-2 (2,1)->-3 (2,2)->4
//
// R4: same structure as R3 (t split across gridDim.z, 49 blocks/CU exactly),
// single change: loads are now CACHED (no nontemporal hint). The harness's
// reset fill re-writes the input right before the timed kernel, so much of the
// 154 MB input is resident in L2/Infinity-Cache; nt loads were discarding that
// residency. Stores stay nontemporal (output is dead data for this kernel --
// don't let it evict the input).

typedef float f4 __attribute__((ext_vector_type(4)));

__global__ __launch_bounds__(192) void Rand2dPatchShift_kernel(
        const f4* __restrict__ x, f4* __restrict__ out) {
    const int n  = blockIdx.x;      // 0..195
    const int b  = blockIdx.y;      // 0..15
    const int t0 = blockIdx.z * 4;  // 0,4,8,12

    const int w  = n % 7;
    const int h  = n / 7;
    const int a3 = w % 3;
    const int b3 = h % 3;

    int s;
    if (a3 == 0)      s = (b3 == 0) ? -4 : (b3 == 1 ? 1 : 2);
    else if (a3 == 1) s = (b3 == 0) ? -1 : (b3 == 1 ? ((n == 8) ? 0 : -1) : 3);
    else              s = (b3 == 0) ? -2 : (b3 == 1 ? -3 : 4);

    // element index (f4 units) of (b, t=0, n, threadIdx.x); t-stride = 196*192
    const int base    = (b * 3136 + n) * 192 + threadIdx.x;  // b*16*196 = b*3136
    const int tstride = 196 * 192;                           // 37632

    f4 v[4];
#pragma unroll
    for (int i = 0; i < 4; ++i) {
        const int tsrc = ((t0 + i) - s + 16) & 15;
        v[i] = x[base + tsrc * tstride];   // cached load (R4 change)
    }
#pragma unroll
    for (int i = 0; i < 4; ++i) {
        __builtin_nontemporal_store(v[i], &out[base + (t0 + i) * tstride]);
    }
}

extern "C" void kernel_launch(void* const* d_in, const int* in_sizes, int n_in,
                              void* d_out, int out_size, void* d_ws, size_t ws_size,
                              hipStream_t stream) {
    const f4* x = (const f4*)d_in[0];
    f4* out = (f4*)d_out;

    dim3 grid(196, 16, 4);  // (n, b, t-quarter) -> 12544 blocks = 49/CU exactly
    dim3 block(192);        // 3 waves, one float4 lane per thread, 4 t's each
    Rand2dPatchShift_kernel<<<grid, block, 0, stream>>>(x, out);
}

// Round 3
// 268.682 us; speedup vs baseline: 1.0075x; 1.0075x over previous
//
#include <hip/hip_runtime.h>

// out[b, t, n, :] = x[b, (t - shift[n]) % 16, n, :]
// x: (B=16, T=16, N=196, c=768) fp32, contiguous.
//
// shift[n] closed form (m=1): w=n%7, h=n/7, a=w%3, b=h%3:
//   (0,0)->-4 (0,1)->1 (0,2)->2
//   (1,0)->-1 (1,1)-> (n==8 ? 0 : -1)   // sticky inv_state: only i=8 sees inv==0
//   (1,2)->3  (2,0)->-2 (2,1)->-3 (2,2)->4
//
// R5: cache-mode matrix experiment, cell (plain load, plain store).
//   measured so far: nt/nt = ~69us kernel; cached-load/nt-store = 97us.
//   m13's 6.29 TB/s copy ceiling on this chip is plain/plain -- test whether
//   the R4 regression was the MIXED mode (write-around stores + allocating
//   loads) rather than cached loads per se. Structure identical to R3/R4:
//   t split across gridDim.z, 49 blocks/CU exactly, 32-bit indexing.

typedef float f4 __attribute__((ext_vector_type(4)));

__global__ __launch_bounds__(192) void Rand2dPatchShift_kernel(
        const f4* __restrict__ x, f4* __restrict__ out) {
    const int n  = blockIdx.x;      // 0..195
    const int b  = blockIdx.y;      // 0..15
    const int t0 = blockIdx.z * 4;  // 0,4,8,12

    const int w  = n % 7;
    const int h  = n / 7;
    const int a3 = w % 3;
    const int b3 = h % 3;

    int s;
    if (a3 == 0)      s = (b3 == 0) ? -4 : (b3 == 1 ? 1 : 2);
    else if (a3 == 1) s = (b3 == 0) ? -1 : (b3 == 1 ? ((n == 8) ? 0 : -1) : 3);
    else              s = (b3 == 0) ? -2 : (b3 == 1 ? -3 : 4);

    // element index (f4 units) of (b, t=0, n, threadIdx.x); t-stride = 196*192
    const int base    = (b * 3136 + n) * 192 + threadIdx.x;  // b*16*196 = b*3136
    const int tstride = 196 * 192;                           // 37632

    f4 v[4];
#pragma unroll
    for (int i = 0; i < 4; ++i) {
        const int tsrc = ((t0 + i) - s + 16) & 15;
        v[i] = x[base + tsrc * tstride];                 // plain cached load
    }
#pragma unroll
    for (int i = 0; i < 4; ++i) {
        out[base + (t0 + i) * tstride] = v[i];           // plain cached store
    }
}

extern "C" void kernel_launch(void* const* d_in, const int* in_sizes, int n_in,
                              void* d_out, int out_size, void* d_ws, size_t ws_size,
                              hipStream_t stream) {
    const f4* x = (const f4*)d_in[0];
    f4* out = (f4*)d_out;

    dim3 grid(196, 16, 4);  // (n, b, t-quarter) -> 12544 blocks = 49/CU exactly
    dim3 block(192);        // 3 waves, one float4 lane per thread, 4 t's each
    Rand2dPatchShift_kernel<<<grid, block, 0, stream>>>(x, out);
}

// Round 4
// 253.340 us; speedup vs baseline: 1.0685x; 1.0606x over previous
//
#include <hip/hip_runtime.h>

// out[b, t, n, :] = x[b, (t - shift[n]) % 16, n, :]
// x: (B=16, T=16, N=196, c=768) fp32, contiguous.
//
// shift[n] closed form (m=1): w=n%7, h=n/7, a=w%3, b=h%3:
//   (0,0)->-4 (0,1)->1 (0,2)->2
//   (1,0)->-1 (1,1)-> (n==8 ? 0 : -1)   // sticky inv_state: only i=8 sees inv==0
//   (1,2)->3  (2,0)->-2 (2,1)->-3 (2,2)->4
//
// R6: SCATTER formulation. Same bytes, roles swapped:
//   x[b, u, n, :] -> out[b, (u + s(n)) & 15, n, :]
// Gather (R3) made concurrent READS scattered across ~9 t-planes at 3 KB
// granularity (page-activate-bound, ~4 TB/s); writes were sequential.
// Scatter makes the concurrent read footprint sequential (block (n,b,u0)
// reads planes u0..u0+3 regardless of shift -- dense copy-like streams) and
// pushes the shuffle to the store side, where the controller's posted-write
// queue can reorder into page-friendly bursts.
// Cache mode: nt/nt (best measured cell; cached loads cost +15-19 us).

typedef float f4 __attribute__((ext_vector_type(4)));

__global__ __launch_bounds__(192) void Rand2dPatchShift_kernel(
        const f4* __restrict__ x, f4* __restrict__ out) {
    const int n  = blockIdx.x;      // 0..195
    const int b  = blockIdx.y;      // 0..15
    const int u0 = blockIdx.z * 4;  // source t: 0,4,8,12

    const int w  = n % 7;
    const int h  = n / 7;
    const int a3 = w % 3;
    const int b3 = h % 3;

    int s;
    if (a3 == 0)      s = (b3 == 0) ? -4 : (b3 == 1 ? 1 : 2);
    else if (a3 == 1) s = (b3 == 0) ? -1 : (b3 == 1 ? ((n == 8) ? 0 : -1) : 3);
    else              s = (b3 == 0) ? -2 : (b3 == 1 ? -3 : 4);

    // element index (f4 units) of (b, t=0, n, threadIdx.x); t-stride = 196*192
    const int base    = (b * 3136 + n) * 192 + threadIdx.x;  // b*16*196 = b*3136
    const int tstride = 196 * 192;                           // 37632

    f4 v[4];
#pragma unroll
    for (int i = 0; i < 4; ++i) {
        // sequential source planes u0..u0+3 (shift-independent -> dense streams)
        v[i] = __builtin_nontemporal_load(&x[base + (u0 + i) * tstride]);
    }
#pragma unroll
    for (int i = 0; i < 4; ++i) {
        const int tdst = ((u0 + i) + s + 16) & 15;   // scattered destination
        __builtin_nontemporal_store(v[i], &out[base + tdst * tstride]);
    }
}

extern "C" void kernel_launch(void* const* d_in, const int* in_sizes, int n_in,
                              void* d_out, int out_size, void* d_ws, size_t ws_size,
                              hipStream_t stream) {
    const f4* x = (const f4*)d_in[0];
    f4* out = (f4*)d_out;

    dim3 grid(196, 16, 4);  // (n, b, source-t-quarter) -> 12544 blocks = 49/CU
    dim3 block(192);        // 3 waves, one float4 lane per thread, 4 t's each
    Rand2dPatchShift_kernel<<<grid, block, 0, stream>>>(x, out);
}